// Round 11
// baseline (136.990 us; speedup 1.0000x reference)
//
#include <hip/hip_runtime.h>

// BatchIndependentLoss: SupCon-style loss, B=2048, V=2, D=256, N=4096.
// loss = -mean_i( lp_i - (W_i - e^{lp}*lp) / u_new[i%B] )
// R11: CODE-FOOTPRINT attack. Every gemm since R1 was a fully-unrolled
// 10-20 KB straight-line body; all pipes <15% busy, wave lifetime ~100K cyc
// vs ~5K work, and dur tracks body size (R8 8KB->29us, R10 14KB->45us),
// invariant to prefetch/atomics/epilogue-cycles/block-size. Theory: tiny
// 1-wave blocks at staggered PCs streaming never-reused code through the
// CU front end -> fetch-bound. Fix: ROLL the loops (~3 KB static body):
//  - K-loop: true 8-iter loop (load -> cvt -> 16 MFMA), TLP hides latency;
//  - epilogue via LDS (64x66 padded tile): lane owns a row -> rolled
//    row pass (E/W row sums, writes t back), rolled col pass (col sums);
//    shuffle trees deleted (1 atomic per lane); Lpos = tile diagonal in
//    tiles p==q^32 (positive j=i^2048 => same within-band offset).
// Structure: memset(E,W2) + gemm(2080 x 64thr, sd==1, exp2 domain) +
// finalize. Math identical to R10 (absmax 0.0).

#define BSZ   2048
#define NROW  4096
#define NB64  64                       // 4096/64 bands
#define NT2   (NB64 * (NB64 + 1) / 2)  // 2080 upper-triangle 64x64 tiles
#define C1    (1.4426950408889634f / 0.07f)   // log2(e)/TEMPERATURE
#define LN2   0.6931471805599453f
#define SROW  66                       // LDS row stride (2-way conflicts only)

typedef __attribute__((ext_vector_type(8))) __bf16 bf16x8;
typedef __attribute__((ext_vector_type(4))) float f32x4;

// contrast row i = v*B + b  ->  features row b*V + v  (fp32, 256 elems)
__device__ __forceinline__ const float* crow_ptr(const float* feats, int i) {
    return feats + (((i & (BSZ - 1)) * 2 + (i >> 11)) << 8);
}

// 8 fp32 -> bf16x8 (RNE)
__device__ __forceinline__ bf16x8 cvt8(float4 a, float4 b) {
    bf16x8 r;
    r[0] = (__bf16)a.x; r[1] = (__bf16)a.y; r[2] = (__bf16)a.z; r[3] = (__bf16)a.w;
    r[4] = (__bf16)b.x; r[5] = (__bf16)b.y; r[6] = (__bf16)b.z; r[7] = (__bf16)b.w;
    return r;
}

// ---------------- rolled symmetric GEMM + stats ----------------------------
// One 64-thread block == one wave == one 64x64 tile of the upper triangle.
__global__ __launch_bounds__(64, 2) void gemm_fused(const float* __restrict__ feats,
        float* __restrict__ E, float* __restrict__ W2, float* __restrict__ Lpos) {
    __shared__ float sacc[64 * SROW];    // 16.5 KB; single wave -> no barriers
    int lane = threadIdx.x;              // 0..63
    int quad = lane >> 4;
    int l15  = lane & 15;

    // triangle decode t -> (p,q), p>=q
    int t = blockIdx.x;
    int p = (int)((sqrtf(8.0f * (float)t + 1.0f) - 1.0f) * 0.5f);
    while ((p + 1) * (p + 2) / 2 <= t) ++p;
    while (p * (p + 1) / 2 > t) --p;
    int q = t - p * (p + 1) / 2;
    int rowBase = q << 6;                // row band (64)
    int colBase = p << 6;                // col band, >= row band
    bool offdiag = (p != q);

    const float* aB = crow_ptr(feats, rowBase + l15) + (quad << 3);
    const float* bB = crow_ptr(feats, colBase + l15) + (quad << 3);

    f32x4 acc[4][4];
    #pragma unroll
    for (int a = 0; a < 4; ++a)
        #pragma unroll
        for (int c = 0; c < 4; ++c) acc[a][c] = (f32x4){0.f, 0.f, 0.f, 0.f};

    // ---- rolled K-loop: 8 iterations, ~110-instr body ----
    #pragma unroll 1
    for (int k = 0; k < 8; ++k) {
        const float* ak = aB + (k << 5);
        const float* bk = bB + (k << 5);
        bf16x8 fa[4], fb[4];
        #pragma unroll
        for (int rt = 0; rt < 4; ++rt) {
            float4 x0 = *(const float4*)(ak + rt * 8192);
            float4 x1 = *(const float4*)(ak + rt * 8192 + 4);
            float4 y0 = *(const float4*)(bk + rt * 8192);
            float4 y1 = *(const float4*)(bk + rt * 8192 + 4);
            fa[rt] = cvt8(x0, x1);
            fb[rt] = cvt8(y0, y1);
        }
        #pragma unroll
        for (int rt = 0; rt < 4; ++rt)
            #pragma unroll
            for (int ct = 0; ct < 4; ++ct)
                acc[rt][ct] = __builtin_amdgcn_mfma_f32_16x16x32_bf16(
                    fa[rt], fb[ct], acc[rt][ct], 0, 0, 0);
    }

    // ---- acc -> LDS (raw dots). C/D layout: col=lane&15, row=quad*4+reg ----
    {
        int wbase = (quad << 2) * SROW + l15;
        #pragma unroll
        for (int rt = 0; rt < 4; ++rt)
            #pragma unroll
            for (int ct = 0; ct < 4; ++ct)
                #pragma unroll
                for (int r = 0; r < 4; ++r)
                    sacc[wbase + ((rt << 4) + r) * SROW + (ct << 4)] = acc[rt][ct][r];
    }

    // ---- row pass: lane owns row `lane`; compute t, E/W row sums; store t
    float eS = 0.0f, wS = 0.0f;
    float* myrow = &sacc[lane * SROW];
    #pragma unroll 1
    for (int j = 0; j < 16; ++j) {
        float4 d = *(float4*)&myrow[j << 2];
        float4 tt;
        tt.x = __builtin_fmaf(d.x, C1, -C1);
        tt.y = __builtin_fmaf(d.y, C1, -C1);
        tt.z = __builtin_fmaf(d.z, C1, -C1);
        tt.w = __builtin_fmaf(d.w, C1, -C1);
        float e0 = __builtin_exp2f(tt.x), e1 = __builtin_exp2f(tt.y);
        float e2 = __builtin_exp2f(tt.z), e3 = __builtin_exp2f(tt.w);
        eS += (e0 + e1) + (e2 + e3);
        wS = __builtin_fmaf(e0, tt.x, wS);
        wS = __builtin_fmaf(e1, tt.y, wS);
        wS = __builtin_fmaf(e2, tt.z, wS);
        wS = __builtin_fmaf(e3, tt.w, wS);
        *(float4*)&myrow[j << 2] = tt;   // keep t for col pass / Lpos
    }
    atomicAdd(&E[rowBase + lane], eS);
    atomicAdd(&W2[rowBase + lane], wS);

    // ---- Lpos: tiles p==q^32 hold positives on the tile DIAGONAL ----
    if (p == (q ^ 32)) {
        float lp = sacc[lane * (SROW + 1)];   // t at (row=lane, col=lane)
        Lpos[rowBase + lane] = lp;            // row view
        Lpos[colBase + lane] = lp;            // col view (same value, sd==1)
    }

    // ---- col pass (offdiag): lane owns column `lane` ----
    if (offdiag) {
        float eC = 0.0f, wC = 0.0f;
        #pragma unroll 1
        for (int j = 0; j < 16; ++j) {
            #pragma unroll
            for (int jj = 0; jj < 4; ++jj) {
                float tt = sacc[((j << 2) + jj) * SROW + lane];
                float e = __builtin_exp2f(tt);
                eC += e;
                wC = __builtin_fmaf(e, tt, wC);
            }
        }
        atomicAdd(&E[colBase + lane], eC);
        atomicAdd(&W2[colBase + lane], wC);
    }
}

// ---------------- finalize: u_new + scalar reduction (exp2 domain) ---------
__global__ __launch_bounds__(1024) void finalize_kernel(const int* __restrict__ index,
        const float* __restrict__ u, const float* __restrict__ E,
        const float* __restrict__ W2, const float* __restrict__ Lpos,
        float* __restrict__ out) {
    __shared__ float unew[BSZ];
    __shared__ float partial[16];
    int tid = threadIdx.x;
    for (int b = tid; b < BSZ; b += 1024) {
        float tp = Lpos[b];
        unew[b] = 0.1f * u[index[b]] + 0.9f * (E[b] - __builtin_exp2f(tp));
    }
    __syncthreads();
    float local = 0.0f;
    for (int i = tid; i < NROW; i += 1024) {
        float tp  = Lpos[i];
        float etp = __builtin_exp2f(tp);
        local += tp - (W2[i] - etp * tp) / unew[i & (BSZ - 1)];
    }
    #pragma unroll
    for (int off = 32; off; off >>= 1) local += __shfl_xor(local, off, 64);
    if ((tid & 63) == 0) partial[tid >> 6] = local;
    __syncthreads();
    if (tid == 0) {
        float s = 0.0f;
        #pragma unroll
        for (int w = 0; w < 16; ++w) s += partial[w];
        out[0] = -LN2 * s / (float)NROW;   // exp2-domain -> nat-log domain
    }
}

extern "C" void kernel_launch(void* const* d_in, const int* in_sizes, int n_in,
                              void* d_out, int out_size, void* d_ws, size_t ws_size,
                              hipStream_t stream) {
    const int*   index = (const int*)d_in[0];
    const float* feats = (const float*)d_in[1];
    const float* u     = (const float*)d_in[2];
    float* out = (float*)d_out;

    // ws: [E | W2 | Lpos]  (3 x 4096 f32 = 48 KB total)
    float* E    = (float*)d_ws;
    float* W2   = E + NROW;
    float* Lpos = W2 + NROW;

    hipMemsetAsync(E, 0, 2 * NROW * sizeof(float), stream);   // zero E, W2
    gemm_fused<<<NT2, 64, 0, stream>>>(feats, E, W2, Lpos);
    finalize_kernel<<<1, 1024, 0, stream>>>(index, u, E, W2, Lpos, out);
}

// Round 12
// 119.674 us; speedup vs baseline: 1.1447x; 1.1447x over previous
//
#include <hip/hip_runtime.h>

// BatchIndependentLoss: SupCon-style loss, B=2048, V=2, D=256, N=4096.
// loss = -mean_i( lp_i - (W_i - e^{lp}*lp) / u_new[i%B] )
// R12: DECOMPOSITION. R6-R11 falsified staging path / prefetch depth /
// block size / epilogue VALU / atomics / code footprint as the ~30-45 us
// gemm invariant; wave lifetime ~80K cyc vs ~5-10K work. Every variant
// fused exp/stats/output onto the GEMM wave at 5-8 waves/CU. Split:
//  P1 gemm_dots: pure GEMM (R8 frag-major CmF loads, depth-2), stores raw
//     dots as bf16 in FRAG LAYOUT (16 x 512B coalesced stores, 17 MB) +
//     R10's validated Lpos diagonal block. No exp/shuffle/atomic tail.
//  P2 expred: full-occupancy (256x256) streaming exp2+reduce over both
//     views of each stored tile; E/W2 plain-stored (single writer/band).
//  finalize unchanged. No memset (all buffers fully written).
// bf16 dot rounding perturbs loss ~1e-3 << 0.284 threshold.
//
// dots layout: short4 at [(t*16 + rt*4 + ct)*64 + lane], components r=0..3
//   = acc[rt][ct][r] for row rt*16+quad*4+r, col ct*16+l15 of tile t (p,q).

#define BSZ   2048
#define NROW  4096
#define NB64  64                       // 4096/64 bands
#define NT2   (NB64 * (NB64 + 1) / 2)  // 2080 upper-triangle 64x64 tiles
#define C1    (1.4426950408889634f / 0.07f)   // log2(e)/TEMPERATURE
#define LN2   0.6931471805599453f

typedef __attribute__((ext_vector_type(8))) __bf16 bf16x8;
typedef __attribute__((ext_vector_type(4))) float f32x4;

__device__ __forceinline__ short f2bs(float x) {
    __bf16 b = (__bf16)x;
    return __builtin_bit_cast(short, b);
}
__device__ __forceinline__ float bs2f(short s) {
    return (float)__builtin_bit_cast(__bf16, s);
}

// contrast row i = v*B + b  ->  features row b*V + v  (fp32, 256 elems)
__device__ __forceinline__ const float* crow_ptr(const float* feats, int i) {
    return feats + (((i & (BSZ - 1)) * 2 + (i >> 11)) << 8);
}

// ---------------- prep: frag-major bf16 pack (validated R8 mapping) --------
__global__ __launch_bounds__(256) void prep_kernel(const float* __restrict__ feats,
        short* __restrict__ CmF) {
    int gid  = blockIdx.x * 256 + threadIdx.x;   // 0..262143
    int quad = gid & 3;
    int l15  = (gid >> 2) & 15;
    int rt   = (gid >> 6) & 3;
    int k    = (gid >> 8) & 7;
    int b    = gid >> 12;
    int srow = (b << 6) + (rt << 4) + l15;
    int kel  = (k << 5) + (quad << 3);
    const float4* fp = (const float4*)(crow_ptr(feats, srow) + kel);
    float4 v0 = fp[0], v1 = fp[1];
    short h[8] = { f2bs(v0.x), f2bs(v0.y), f2bs(v0.z), f2bs(v0.w),
                   f2bs(v1.x), f2bs(v1.y), f2bs(v1.z), f2bs(v1.w) };
    *(int4*)(CmF + gid * 8) = *(int4*)h;
}

// ---------------- P1: pure symmetric GEMM -> bf16 dots + Lpos --------------
// One 64-thread block == one wave == one 64x64 upper-triangle tile.
__global__ __launch_bounds__(64, 2) void gemm_dots(const short* __restrict__ CmF,
        short4* __restrict__ dots, float* __restrict__ Lpos) {
    int lane = threadIdx.x;          // 0..63
    int quad = lane >> 4;
    int l15  = lane & 15;

    // triangle decode t -> (p,q), p>=q
    int t = blockIdx.x;
    int p = (int)((sqrtf(8.0f * (float)t + 1.0f) - 1.0f) * 0.5f);
    while ((p + 1) * (p + 2) / 2 <= t) ++p;
    while (p * (p + 1) / 2 > t) --p;
    int q = t - p * (p + 1) / 2;

    const short* aB = CmF + q * 16384 + ((l15 << 2) + quad) * 8;
    const short* bB = CmF + p * 16384 + ((l15 << 2) + quad) * 8;

    f32x4 acc[4][4];
    #pragma unroll
    for (int a = 0; a < 4; ++a)
        #pragma unroll
        for (int c = 0; c < 4; ++c) acc[a][c] = (f32x4){0.f, 0.f, 0.f, 0.f};

    // depth-2 software pipeline (R8-validated): 3 rotating fragment buffers
    bf16x8 aF[3][4], bF[3][4];
    #pragma unroll
    for (int rt = 0; rt < 4; ++rt) {
        aF[0][rt] = *(const bf16x8*)(aB + (0 * 4 + rt) * 512);
        bF[0][rt] = *(const bf16x8*)(bB + (0 * 4 + rt) * 512);
    }
    #pragma unroll
    for (int rt = 0; rt < 4; ++rt) {
        aF[1][rt] = *(const bf16x8*)(aB + (1 * 4 + rt) * 512);
        bF[1][rt] = *(const bf16x8*)(bB + (1 * 4 + rt) * 512);
    }
    #pragma unroll
    for (int k = 0; k < 8; ++k) {
        int cur = k % 3;
        int nxt = (k + 2) % 3;
        if (k < 6) {
            #pragma unroll
            for (int rt = 0; rt < 4; ++rt) {
                aF[nxt][rt] = *(const bf16x8*)(aB + ((k + 2) * 4 + rt) * 512);
                bF[nxt][rt] = *(const bf16x8*)(bB + ((k + 2) * 4 + rt) * 512);
            }
        }
        #pragma unroll
        for (int rt = 0; rt < 4; ++rt)
            #pragma unroll
            for (int ct = 0; ct < 4; ++ct)
                acc[rt][ct] = __builtin_amdgcn_mfma_f32_16x16x32_bf16(
                    aF[cur][rt], bF[cur][ct], acc[rt][ct], 0, 0, 0);
    }

    // Lpos: tiles p==q^32 hold positives (j=i^2048) on the tile diagonal.
    // Row/col views equal under sd==1. (R10-validated block.)
    if (p == (q ^ 32)) {
        if (quad == (l15 >> 2)) {
            int r = l15 & 3;
            #pragma unroll
            for (int rt = 0; rt < 4; ++rt) {
                float lp = __builtin_fmaf(acc[rt][rt][r], C1, -C1);
                Lpos[(q << 6) + rt * 16 + l15] = lp;
                Lpos[(p << 6) + rt * 16 + l15] = lp;
            }
        }
    }

    // store raw dots as bf16 in frag layout: 16 coalesced 512B stores
    #pragma unroll
    for (int rt = 0; rt < 4; ++rt)
        #pragma unroll
        for (int ct = 0; ct < 4; ++ct) {
            short4 h = make_short4(f2bs(acc[rt][ct][0]), f2bs(acc[rt][ct][1]),
                                   f2bs(acc[rt][ct][2]), f2bs(acc[rt][ct][3]));
            dots[((t << 4) + (rt << 2) + ct) * 64 + lane] = h;
        }
}

// ---------------- P2: full-occupancy exp2 + per-band E/W reduction ---------
// Block = (band b, 16-row group w4): 256 blocks x 256 threads. The band's
// 64 tiles (row-view: q==b, p=b..63; col-view: p==b, q<b) are split across
// the 4 waves; per-lane partials -> shfl reduce -> LDS atomic -> plain store.
__global__ __launch_bounds__(256) void expred_kernel(const short4* __restrict__ dots,
        float* __restrict__ E, float* __restrict__ W2) {
    __shared__ float sE[16], sW[16];
    int b   = blockIdx.x >> 2;
    int w4  = blockIdx.x & 3;
    int tid = threadIdx.x;
    int wave = tid >> 6, lane = tid & 63;
    int quad = lane >> 4, l15 = lane & 15;
    if (tid < 16) { sE[tid] = 0.0f; sW[tid] = 0.0f; }
    __syncthreads();

    int nrow_t = NB64 - b;               // # row-view tiles
    float Ep[4] = {}, Wp[4] = {};        // row-view: rows w4*16+quad*4+r
    float Ec = 0.0f, Wc = 0.0f;          // col-view: col  w4*16+l15

    for (int idx = wave; idx < NB64; idx += 4) {
        if (idx < nrow_t) {              // row view: tile (p=b+idx, q=b)
            int pp = b + idx;
            int t  = pp * (pp + 1) / 2 + b;
            #pragma unroll
            for (int ct = 0; ct < 4; ++ct) {
                short4 v = dots[((t << 4) + (w4 << 2) + ct) * 64 + lane];
                #pragma unroll
                for (int r = 0; r < 4; ++r) {
                    float d  = bs2f(((short*)&v)[r]);
                    float tt = __builtin_fmaf(d, C1, -C1);
                    float e  = __builtin_exp2f(tt);
                    Ep[r] += e;
                    Wp[r] = __builtin_fmaf(e, tt, Wp[r]);
                }
            }
        } else {                         // col view: tile (p=b, q=idx-nrow_t)
            int t = b * (b + 1) / 2 + (idx - nrow_t);
            #pragma unroll
            for (int q2 = 0; q2 < 4; ++q2) {
                short4 v = dots[((t << 4) + (quad << 2) + w4) * 64 + (q2 << 4) + l15];
                #pragma unroll
                for (int r = 0; r < 4; ++r) {
                    float d  = bs2f(((short*)&v)[r]);
                    float tt = __builtin_fmaf(d, C1, -C1);
                    float e  = __builtin_exp2f(tt);
                    Ec += e;
                    Wc = __builtin_fmaf(e, tt, Wc);
                }
            }
        }
    }

    // row-view partials: reduce over the 16 l15 lanes sharing each row
    #pragma unroll
    for (int r = 0; r < 4; ++r) {
        float e = Ep[r], w = Wp[r];
        #pragma unroll
        for (int off = 1; off < 16; off <<= 1) {
            e += __shfl_xor(e, off, 64);
            w += __shfl_xor(w, off, 64);
        }
        if (l15 == 0) {
            atomicAdd(&sE[(quad << 2) + r], e);
            atomicAdd(&sW[(quad << 2) + r], w);
        }
    }
    // col-view partials: reduce over the 4 quads sharing each col
    {
        float e = Ec, w = Wc;
        e += __shfl_xor(e, 16, 64);  w += __shfl_xor(w, 16, 64);
        e += __shfl_xor(e, 32, 64);  w += __shfl_xor(w, 32, 64);
        if (quad == 0) {
            atomicAdd(&sE[l15], e);
            atomicAdd(&sW[l15], w);
        }
    }
    __syncthreads();
    if (tid < 16) {
        int row = (b << 6) + (w4 << 4) + tid;
        E[row]  = sE[tid];
        W2[row] = sW[tid];
    }
}

// ---------------- finalize: u_new + scalar reduction (exp2 domain) ---------
__global__ __launch_bounds__(1024) void finalize_kernel(const int* __restrict__ index,
        const float* __restrict__ u, const float* __restrict__ E,
        const float* __restrict__ W2, const float* __restrict__ Lpos,
        float* __restrict__ out) {
    __shared__ float unew[BSZ];
    __shared__ float partial[16];
    int tid = threadIdx.x;
    for (int b = tid; b < BSZ; b += 1024) {
        float tp = Lpos[b];
        unew[b] = 0.1f * u[index[b]] + 0.9f * (E[b] - __builtin_exp2f(tp));
    }
    __syncthreads();
    float local = 0.0f;
    for (int i = tid; i < NROW; i += 1024) {
        float tp  = Lpos[i];
        float etp = __builtin_exp2f(tp);
        local += tp - (W2[i] - etp * tp) / unew[i & (BSZ - 1)];
    }
    #pragma unroll
    for (int off = 32; off; off >>= 1) local += __shfl_xor(local, off, 64);
    if ((tid & 63) == 0) partial[tid >> 6] = local;
    __syncthreads();
    if (tid == 0) {
        float s = 0.0f;
        #pragma unroll
        for (int w = 0; w < 16; ++w) s += partial[w];
        out[0] = -LN2 * s / (float)NROW;   // exp2-domain -> nat-log domain
    }
}

extern "C" void kernel_launch(void* const* d_in, const int* in_sizes, int n_in,
                              void* d_out, int out_size, void* d_ws, size_t ws_size,
                              hipStream_t stream) {
    const int*   index = (const int*)d_in[0];
    const float* feats = (const float*)d_in[1];
    const float* u     = (const float*)d_in[2];
    float* out = (float*)d_out;

    // ws: CmF @0 (2 MB) | dots @2MB (17 MB) | E/W2/Lpos @20MB (48 KB)
    short*  CmF  = (short*)d_ws;
    short4* dots = (short4*)((char*)d_ws + (2u << 20));
    float*  E    = (float*)((char*)d_ws + (20u << 20));
    float*  W2   = E + NROW;
    float*  Lpos = W2 + NROW;

    prep_kernel<<<1024, 256, 0, stream>>>(feats, CmF);
    gemm_dots<<<NT2, 64, 0, stream>>>(CmF, dots, Lpos);
    expred_kernel<<<256, 256, 0, stream>>>(dots, E, W2);
    finalize_kernel<<<1, 1024, 0, stream>>>(index, u, E, W2, Lpos, out);
}